// Round 3
// baseline (699.299 us; speedup 1.0000x reference)
//
#include <hip/hip_runtime.h>

#define N_NODES 100000
#define N_EDGES 1600000
#define CH 64
#define NLAYERS 3
#define NBUCK 391          // ceil(100000/256) buckets of 256 dst nodes
#define EPB 4096           // edges per partition block
#define STASH 20

static __device__ __forceinline__ float4 ld4(const float* p){ return *(const float4*)p; }

// ---- A0: bucket histogram (bucket = dst>>8) ----
__global__ __launch_bounds__(256) void bhist_kernel(const int* __restrict__ dst, int* __restrict__ bcnt){
  __shared__ int h[NBUCK];
  int tid = threadIdx.x;
  for (int i = tid; i < NBUCK; i += 256) h[i] = 0;
  __syncthreads();
  int base = blockIdx.x * EPB;
  #pragma unroll
  for (int k = 0; k < EPB/256; ++k) {
    int e = base + k*256 + tid;
    if (e < N_EDGES) atomicAdd(&h[dst[e] >> 8], 1);
  }
  __syncthreads();
  for (int i = tid; i < NBUCK; i += 256) if (h[i]) atomicAdd(&bcnt[i], h[i]);
}

// ---- A1: scan buckets -> bstart[0..NBUCK], btail working copy ----
__global__ __launch_bounds__(512) void bscan_kernel(const int* __restrict__ bcnt,
                                                    int* __restrict__ bstart, int* __restrict__ btail){
  __shared__ int s[512];
  int t = threadIdx.x;
  int v = (t < NBUCK) ? bcnt[t] : 0;
  s[t] = v; __syncthreads();
  #pragma unroll
  for (int o = 1; o < 512; o <<= 1){
    int u = (t >= o) ? s[t-o] : 0;
    __syncthreads();
    s[t] += u;
    __syncthreads();
  }
  if (t <= NBUCK) {
    int ex = (t == 0) ? 0 : s[t-1];
    bstart[t] = ex;
    if (t < NBUCK) btail[t] = ex;
  }
}

// ---- A2: partition edges into bucket-contiguous (src,dst) pairs ----
__global__ __launch_bounds__(256) void part_kernel(const int* __restrict__ src, const int* __restrict__ dst,
                                                   int* __restrict__ btail, int2* __restrict__ pairs){
  __shared__ int lpos[NBUCK];
  __shared__ int gb[NBUCK];
  int tid = threadIdx.x;
  for (int i = tid; i < NBUCK; i += 256) lpos[i] = 0;
  __syncthreads();
  int base = blockIdx.x * EPB;
  int es[EPB/256], ed[EPB/256], er[EPB/256];
  #pragma unroll
  for (int k = 0; k < EPB/256; ++k) {
    int e = base + k*256 + tid;
    if (e < N_EDGES) {
      es[k] = src[e];
      ed[k] = dst[e];
      er[k] = atomicAdd(&lpos[ed[k] >> 8], 1);
    }
  }
  __syncthreads();
  for (int i = tid; i < NBUCK; i += 256) {
    int c = lpos[i];
    gb[i] = c ? atomicAdd(&btail[i], c) : 0;
  }
  __syncthreads();
  #pragma unroll
  for (int k = 0; k < EPB/256; ++k) {
    int e = base + k*256 + tid;
    if (e < N_EDGES) pairs[gb[ed[k] >> 8] + er[k]] = make_int2(es[k], ed[k]);
  }
}

// ---- B: per-bucket CSR build (off + srclist) ----
__global__ __launch_bounds__(256) void csr_kernel(const int2* __restrict__ pairs, const int* __restrict__ bstart,
                                                  int* __restrict__ off, int* __restrict__ srclist){
  __shared__ int c[256];
  __shared__ int s[256];
  __shared__ int cur[256];
  int t = threadIdx.x;
  int b = blockIdx.x;
  int e0 = bstart[b], e1 = bstart[b+1];
  c[t] = 0;
  __syncthreads();
  int2 st[STASH];
  int k = 0;
  for (int i = e0 + t; i < e1; i += 256, ++k) {
    int2 pr = pairs[i];
    if (k < STASH) st[k] = pr;
    atomicAdd(&c[pr.y & 255], 1);
  }
  __syncthreads();
  int v = c[t];
  s[t] = v; __syncthreads();
  #pragma unroll
  for (int o = 1; o < 256; o <<= 1){
    int u = (t >= o) ? s[t-o] : 0;
    __syncthreads();
    s[t] += u;
    __syncthreads();
  }
  int excl = s[t] - v;
  cur[t] = excl;
  int n = (b << 8) + t;
  if (n <= N_NODES) off[n] = e0 + excl;
  // node at boundary (b+1)<<8 is written by block b+1 at t=0; node N_NODES by b=390,t=160 (count 0).
  __syncthreads();
  k = 0;
  for (int i = e0 + t; i < e1; i += 256, ++k) {
    int2 pr = (k < STASH) ? st[k] : pairs[i];
    int p = atomicAdd(&cur[pr.y & 255], 1);
    srclist[e0 + p] = pr.x;
  }
}

// ---- fold BN into weights/biases ----
__global__ __launch_bounds__(256) void prep_kernel(
    const float* __restrict__ W1, const float* __restrict__ b1,
    const float* __restrict__ g1, const float* __restrict__ be1,
    const float* __restrict__ W2, const float* __restrict__ b2,
    const float* __restrict__ g2, const float* __restrict__ be2,
    const float* __restrict__ bng, const float* __restrict__ bnb,
    float* __restrict__ Wf, float* __restrict__ bf, float* __restrict__ ogb){
  const float s = 0.9999950000374997f;   // 1/sqrt(1+1e-5)
  int i = blockIdx.x*256 + threadIdx.x;
  if (i < NLAYERS*4096) {
    int l = i >> 12, rem = i & 4095, j = rem & 63;
    Wf[l*8192 + rem]        = W1[i] * g1[l*64+j] * s;
    Wf[l*8192 + 4096 + rem] = W2[i] * g2[l*64+j] * s;
  }
  if (i < NLAYERS*64) {
    int l = i >> 6, j = i & 63;
    bf[l*128 + j]      = b1[i]*g1[i]*s + be1[i];
    bf[l*128 + 64 + j] = b2[i]*g2[i]*s + be2[i];
    ogb[i]                 = bng[i]*s;
    ogb[NLAYERS*64 + i]    = bnb[i];
  }
}

// ---- fused: gather-agg into LDS -> MLP(2x GEMM+BN+ReLU) -> outer BN (+ReLU) ----
// READ buffer x and WRITE buffer out must be DIFFERENT allocations (WAR race otherwise).
__global__ __launch_bounds__(256) void layer_kernel(const float* __restrict__ x, const int* __restrict__ off,
                                                    const int* __restrict__ srclist, const float* __restrict__ eps,
                                                    const float* __restrict__ Wf, const float* __restrict__ bf,
                                                    const float* __restrict__ ogb, int layer,
                                                    float* __restrict__ out, int relu_out){
  __shared__ __align__(16) float W1s[64*64];
  __shared__ __align__(16) float W2s[64*64];
  __shared__ __align__(16) float Hs[64*68];   // +4 pad
  int tid = threadIdx.x;
  const float* Wg = Wf + layer*8192;
  #pragma unroll
  for (int it = 0; it < 4; ++it) {
    int i = (tid + it*256) * 4;
    *(float4*)&W1s[i] = ld4(Wg + i);
    *(float4*)&W2s[i] = ld4(Wg + 4096 + i);
  }
  // gather-aggregate 64 nodes into Hs
  float ep = 1.0f + eps[layer];
  int c = (tid & 15) << 2;
  int grp = tid >> 4;
  #pragma unroll
  for (int p = 0; p < 4; ++p) {
    int nl = p*16 + grp;
    int n = blockIdx.x*64 + nl;
    float ax = 0.f, ay = 0.f, az = 0.f, aw = 0.f;
    if (n < N_NODES) {
      int e0 = off[n], e1 = off[n+1];
      for (int e = e0; e < e1; ++e) {
        int sidx = srclist[e];
        float4 v = ld4(x + (size_t)sidx*CH + c);
        ax += v.x; ay += v.y; az += v.z; aw += v.w;
      }
      float4 xv = ld4(x + (size_t)n*CH + c);
      ax = fmaf(ep, xv.x, ax); ay = fmaf(ep, xv.y, ay);
      az = fmaf(ep, xv.z, az); aw = fmaf(ep, xv.w, aw);
    }
    *(float4*)&Hs[nl*68 + c] = make_float4(ax, ay, az, aw);
  }
  __syncthreads();

  int nq = (tid & 15) << 2;
  int j0 = (tid >> 4) << 2;
  const float4 bias1 = ld4(bf + layer*128 + j0);
  const float4 bias2 = ld4(bf + layer*128 + 64 + j0);
  const float4 og4   = ld4(ogb + layer*64 + j0);
  const float4 ob4   = ld4(ogb + NLAYERS*64 + layer*64 + j0);

  float acc[4][4];
  #pragma unroll
  for (int r = 0; r < 4; ++r){ acc[r][0]=bias1.x; acc[r][1]=bias1.y; acc[r][2]=bias1.z; acc[r][3]=bias1.w; }

  for (int k = 0; k < 64; k += 4) {
    float4 a[4], b[4];
    #pragma unroll
    for (int r = 0; r < 4; ++r) a[r] = *(const float4*)&Hs[(nq+r)*68 + k];
    #pragma unroll
    for (int kk = 0; kk < 4; ++kk) b[kk] = *(const float4*)&W1s[(k+kk)*64 + j0];
    #pragma unroll
    for (int r = 0; r < 4; ++r){
      const float* ar = (const float*)&a[r];
      #pragma unroll
      for (int kk = 0; kk < 4; ++kk){
        float av = ar[kk];
        acc[r][0] = fmaf(av, b[kk].x, acc[r][0]);
        acc[r][1] = fmaf(av, b[kk].y, acc[r][1]);
        acc[r][2] = fmaf(av, b[kk].z, acc[r][2]);
        acc[r][3] = fmaf(av, b[kk].w, acc[r][3]);
      }
    }
  }
  __syncthreads();
  #pragma unroll
  for (int r = 0; r < 4; ++r){
    float4 hv = make_float4(fmaxf(acc[r][0],0.f), fmaxf(acc[r][1],0.f),
                            fmaxf(acc[r][2],0.f), fmaxf(acc[r][3],0.f));
    *(float4*)&Hs[(nq+r)*68 + j0] = hv;
  }
  __syncthreads();

  #pragma unroll
  for (int r = 0; r < 4; ++r){ acc[r][0]=bias2.x; acc[r][1]=bias2.y; acc[r][2]=bias2.z; acc[r][3]=bias2.w; }
  for (int k = 0; k < 64; k += 4) {
    float4 a[4], b[4];
    #pragma unroll
    for (int r = 0; r < 4; ++r) a[r] = *(const float4*)&Hs[(nq+r)*68 + k];
    #pragma unroll
    for (int kk = 0; kk < 4; ++kk) b[kk] = *(const float4*)&W2s[(k+kk)*64 + j0];
    #pragma unroll
    for (int r = 0; r < 4; ++r){
      const float* ar = (const float*)&a[r];
      #pragma unroll
      for (int kk = 0; kk < 4; ++kk){
        float av = ar[kk];
        acc[r][0] = fmaf(av, b[kk].x, acc[r][0]);
        acc[r][1] = fmaf(av, b[kk].y, acc[r][1]);
        acc[r][2] = fmaf(av, b[kk].z, acc[r][2]);
        acc[r][3] = fmaf(av, b[kk].w, acc[r][3]);
      }
    }
  }

  #pragma unroll
  for (int r = 0; r < 4; ++r){
    int gnode = blockIdx.x*64 + nq + r;
    if (gnode < N_NODES) {
      float o0 = fmaf(og4.x, fmaxf(acc[r][0],0.f), ob4.x);
      float o1 = fmaf(og4.y, fmaxf(acc[r][1],0.f), ob4.y);
      float o2 = fmaf(og4.z, fmaxf(acc[r][2],0.f), ob4.z);
      float o3 = fmaf(og4.w, fmaxf(acc[r][3],0.f), ob4.w);
      if (relu_out){ o0=fmaxf(o0,0.f); o1=fmaxf(o1,0.f); o2=fmaxf(o2,0.f); o3=fmaxf(o3,0.f); }
      *(float4*)(out + (size_t)gnode*CH + j0) = make_float4(o0,o1,o2,o3);
    }
  }
}

extern "C" void kernel_launch(void* const* d_in, const int* in_sizes, int n_in,
                              void* d_out, int out_size, void* d_ws, size_t ws_size,
                              hipStream_t stream) {
  const float* x0  = (const float*)d_in[0];
  const int*   ei  = (const int*)d_in[1];
  const float* eps = (const float*)d_in[2];
  const float* W1  = (const float*)d_in[3];
  const float* b1  = (const float*)d_in[4];
  const float* g1  = (const float*)d_in[5];
  const float* be1 = (const float*)d_in[6];
  const float* W2  = (const float*)d_in[7];
  const float* b2  = (const float*)d_in[8];
  const float* g2  = (const float*)d_in[9];
  const float* be2 = (const float*)d_in[10];
  const float* bng = (const float*)d_in[11];
  const float* bnb = (const float*)d_in[12];
  const int* src = ei;
  const int* dst = ei + N_EDGES;
  float* OUT = (float*)d_out;

  char* p = (char*)d_ws;
  auto carve = [&](size_t bytes)->char*{ char* r = p; p += (bytes + 255) & ~(size_t)255; return r; };
  int*   off     = (int*)carve((N_NODES+1)*sizeof(int));
  int*   bcnt    = (int*)carve(NBUCK*sizeof(int));
  int*   bstart  = (int*)carve((NBUCK+1)*sizeof(int));
  int*   btail   = (int*)carve(NBUCK*sizeof(int));
  // pairs (12.8 MB) is dead after csr_kernel; T (25.6 MB) aliases the same region.
  char*  big     = carve((size_t)N_NODES*CH*sizeof(float));   // 25.6 MB
  int2*  pairs   = (int2*)big;
  float* T       = (float*)big;
  int*   srclist = (int*)carve((size_t)N_EDGES*sizeof(int));
  float* Wf      = (float*)carve((size_t)NLAYERS*2*4096*sizeof(float));
  float* bfb     = (float*)carve((size_t)NLAYERS*2*64*sizeof(float));
  float* ogb     = (float*)carve((size_t)2*NLAYERS*64*sizeof(float));

  const int npart = (N_EDGES + EPB - 1)/EPB;   // 391
  hipMemsetAsync(bcnt, 0, NBUCK*sizeof(int), stream);
  bhist_kernel<<<npart, 256, 0, stream>>>(dst, bcnt);
  bscan_kernel<<<1, 512, 0, stream>>>(bcnt, bstart, btail);
  part_kernel<<<npart, 256, 0, stream>>>(src, dst, btail, pairs);
  csr_kernel<<<NBUCK, 256, 0, stream>>>(pairs, bstart, off, srclist);
  prep_kernel<<<48, 256, 0, stream>>>(W1,b1,g1,be1,W2,b2,g2,be2,bng,bnb,Wf,bfb,ogb);

  const int nlb = (N_NODES + 63)/64;
  // Ping-pong: read-set and write-set never alias within a layer.
  // l0: x0 -> OUT, l1: OUT -> T, l2: T -> OUT (final result in d_out).
  layer_kernel<<<nlb, 256, 0, stream>>>(x0,  off, srclist, eps, Wf, bfb, ogb, 0, OUT, 1);
  layer_kernel<<<nlb, 256, 0, stream>>>(OUT, off, srclist, eps, Wf, bfb, ogb, 1, T,   1);
  layer_kernel<<<nlb, 256, 0, stream>>>(T,   off, srclist, eps, Wf, bfb, ogb, 2, OUT, 0);
}